// Round 1
// baseline (492.832 us; speedup 1.0000x reference)
//
#include <hip/hip_runtime.h>

#define N_NODES 50000
#define N_EDGES 1600000
#define IN_CH 128
#define HEADS 4
#define OUT_CH 16
#define HC 64                      // HEADS*OUT_CH
#define E_FULL (N_EDGES + N_NODES)
#define NEG_SLOPE 0.2f

// Kernel A: h = x @ W (per-wave node, lane = output channel), fused per-node
// attention scalars s_src[n][h] = <h[n][h], a_src[h]>, s_dst likewise.
__global__ __launch_bounds__(256) void gemm_h_kernel(
    const float* __restrict__ x, const float* __restrict__ weight,
    const float* __restrict__ att, float* __restrict__ h,
    float* __restrict__ s_src, float* __restrict__ s_dst)
{
    __shared__ float w_lds[IN_CH * HC];   // 32 KB
    __shared__ float x_lds[4 * IN_CH];    // 2 KB
    const int tid = threadIdx.x;
    const int nbase = blockIdx.x * 4;

    for (int i = tid; i < IN_CH * HC; i += 256) w_lds[i] = weight[i];
    for (int i = tid; i < 4 * IN_CH; i += 256) {
        int n = nbase + i / IN_CH;
        x_lds[i] = (n < N_NODES) ? x[(size_t)n * IN_CH + (i % IN_CH)] : 0.f;
    }
    __syncthreads();

    const int w = tid >> 6;        // wave id == local node
    const int lane = tid & 63;     // output channel
    const int n = nbase + w;

    float acc = 0.f;
    #pragma unroll 8
    for (int k = 0; k < IN_CH; ++k)
        acc = fmaf(x_lds[w * IN_CH + k], w_lds[k * HC + lane], acc);

    if (n < N_NODES) h[(size_t)n * HC + lane] = acc;

    // per-head reduction: head hd = lane/16, c = lane%16
    const int hd = lane >> 4, c = lane & 15;
    // att_weight flat: [hd*32 + j], j<16 -> a_src, j>=16 -> a_dst
    float ts = acc * att[hd * 32 + c];
    float td = acc * att[hd * 32 + 16 + c];
    #pragma unroll
    for (int m = 8; m >= 1; m >>= 1) {
        ts += __shfl_xor(ts, m, 64);
        td += __shfl_xor(td, m, 64);
    }
    if (c == 0 && n < N_NODES) {
        s_src[n * HEADS + hd] = ts;
        s_dst[n * HEADS + hd] = td;
    }
}

// Kernel B: out init = bias + self-loop message; also alpha/edge_index tails.
__global__ __launch_bounds__(256) void node_init_kernel(
    const float* __restrict__ h, const float* __restrict__ s_src,
    const float* __restrict__ s_dst, const float* __restrict__ bias,
    float* __restrict__ out, float* __restrict__ eif, float* __restrict__ alpha)
{
    int g = blockIdx.x * 256 + threadIdx.x;
    if (g >= N_NODES * HC) return;
    const int n = g >> 6, lane = g & 63, hd = lane >> 4;

    float s = s_src[n * HEADS + hd] + s_dst[n * HEADS + hd];
    float a = (s >= 0.f) ? s : NEG_SLOPE * s;       // ea = 1 for self-loops
    out[g] = bias[lane] + a * h[g];

    if (lane < HEADS) {
        float s2 = s_src[n * HEADS + lane] + s_dst[n * HEADS + lane];
        float a2 = (s2 >= 0.f) ? s2 : NEG_SLOPE * s2;
        alpha[(size_t)(N_EDGES + n) * HEADS + lane] = a2;
    }
    if (lane == 4) eif[N_EDGES + n] = (float)n;                     // row tail
    if (lane == 5) eif[(size_t)E_FULL + N_EDGES + n] = (float)n;    // col tail
}

// Kernel C: per-edge scatter. One 64-lane wave per edge, lane = channel.
__global__ __launch_bounds__(256) void edge_kernel(
    const int* __restrict__ ei, const float* __restrict__ ea,
    const float* __restrict__ h, const float* __restrict__ s_src,
    const float* __restrict__ s_dst, float* __restrict__ out,
    float* __restrict__ eif, float* __restrict__ alpha)
{
    size_t g = (size_t)blockIdx.x * 256 + threadIdx.x;
    size_t e = g >> 6;
    if (e >= N_EDGES) return;
    const int lane = (int)(g & 63), hd = lane >> 4;

    const int r = ei[e];               // edge_index[0][e]
    const int c = ei[N_EDGES + e];     // edge_index[1][e]

    float s = s_src[r * HEADS + hd] + s_dst[c * HEADS + hd];
    float a = ((s >= 0.f) ? s : NEG_SLOPE * s) * ea[e * HEADS + hd];
    float hv = h[(size_t)c * HC + lane];
    atomicAdd(&out[(size_t)r * HC + lane], a * hv);

    if (lane < HEADS) {
        float s2 = s_src[r * HEADS + lane] + s_dst[c * HEADS + lane];
        float a2 = ((s2 >= 0.f) ? s2 : NEG_SLOPE * s2) * ea[e * HEADS + lane];
        alpha[e * HEADS + lane] = a2;
    }
    if (lane == 4) eif[e] = (float)r;
    if (lane == 5) eif[(size_t)E_FULL + e] = (float)c;
}

extern "C" void kernel_launch(void* const* d_in, const int* in_sizes, int n_in,
                              void* d_out, int out_size, void* d_ws, size_t ws_size,
                              hipStream_t stream) {
    const float* x      = (const float*)d_in[0];
    const int*   ei     = (const int*)  d_in[1];
    const float* ea     = (const float*)d_in[2];
    const float* weight = (const float*)d_in[3];
    const float* att    = (const float*)d_in[4];
    const float* bias   = (const float*)d_in[5];

    float* out   = (float*)d_out;                    // N_NODES*HC
    float* eif   = out + (size_t)N_NODES * HC;       // 2*E_FULL (as float)
    float* alpha = eif + (size_t)2 * E_FULL;         // E_FULL*HEADS

    float* h     = (float*)d_ws;                     // N_NODES*HC
    float* s_src = h + (size_t)N_NODES * HC;         // N_NODES*HEADS
    float* s_dst = s_src + (size_t)N_NODES * HEADS;  // N_NODES*HEADS

    gemm_h_kernel<<<(N_NODES + 3) / 4, 256, 0, stream>>>(x, weight, att, h, s_src, s_dst);
    node_init_kernel<<<(N_NODES * HC + 255) / 256, 256, 0, stream>>>(
        h, s_src, s_dst, bias, out, eif, alpha);
    edge_kernel<<<(int)(((size_t)N_EDGES * 64 + 255) / 256), 256, 0, stream>>>(
        ei, ea, h, s_src, s_dst, out, eif, alpha);
}

// Round 3
// 322.635 us; speedup vs baseline: 1.5275x; 1.5275x over previous
//
#include <hip/hip_runtime.h>

#define N_NODES 50000
#define N_EDGES 1600000
#define IN_CH 128
#define HEADS 4
#define OUT_CH 16
#define HC 64                      // HEADS*OUT_CH
#define E_FULL (N_EDGES + N_NODES)
#define NEG_SLOPE 0.2f
#define SCAN_BLOCKS ((N_NODES + 255) / 256)   // 196

__device__ __forceinline__ float leaky(float s) { return s >= 0.f ? s : NEG_SLOPE * s; }

// ---------------- Kernel A: h = x @ W, fused per-node attention scalars ----
__global__ __launch_bounds__(256) void gemm_h_kernel(
    const float* __restrict__ x, const float* __restrict__ weight,
    const float* __restrict__ att, float* __restrict__ h,
    float* __restrict__ s_src, float* __restrict__ s_dst)
{
    __shared__ float w_lds[IN_CH * HC];   // 32 KB
    __shared__ float x_lds[4 * IN_CH];    // 2 KB
    const int tid = threadIdx.x;
    const int nbase = blockIdx.x * 4;

    for (int i = tid; i < IN_CH * HC; i += 256) w_lds[i] = weight[i];
    for (int i = tid; i < 4 * IN_CH; i += 256) {
        int n = nbase + i / IN_CH;
        x_lds[i] = (n < N_NODES) ? x[(size_t)n * IN_CH + (i % IN_CH)] : 0.f;
    }
    __syncthreads();

    const int w = tid >> 6;        // wave id == local node
    const int lane = tid & 63;     // output channel
    const int n = nbase + w;

    float acc = 0.f;
    #pragma unroll 8
    for (int k = 0; k < IN_CH; ++k)
        acc = fmaf(x_lds[w * IN_CH + k], w_lds[k * HC + lane], acc);

    if (n < N_NODES) h[(size_t)n * HC + lane] = acc;

    const int hd = lane >> 4, c = lane & 15;
    float ts = acc * att[hd * 32 + c];
    float td = acc * att[hd * 32 + 16 + c];
    #pragma unroll
    for (int m = 8; m >= 1; m >>= 1) {
        ts += __shfl_xor(ts, m, 64);
        td += __shfl_xor(td, m, 64);
    }
    if (c == 0 && n < N_NODES) {
        s_src[n * HEADS + hd] = ts;
        s_dst[n * HEADS + hd] = td;
    }
}

// ---------------- Kernel B: row histogram + edge_index_full output ---------
__global__ __launch_bounds__(256) void hist_kernel(
    const int* __restrict__ ei, unsigned* __restrict__ counts,
    float* __restrict__ eif)
{
    int e = blockIdx.x * 256 + threadIdx.x;
    if (e >= N_EDGES) return;
    const int r = ei[e];
    const int c = ei[N_EDGES + e];
    atomicAdd(&counts[r], 1u);
    eif[e] = (float)r;
    eif[(size_t)E_FULL + e] = (float)c;
}

// ---------------- Scan: counts -> exclusive offsets (3 tiny kernels) ------
__device__ __forceinline__ unsigned block_excl_scan(unsigned v, unsigned* total,
                                                    int tid) {
    const int lane = tid & 63, wid = tid >> 6;
    unsigned x = v;
    #pragma unroll
    for (int d = 1; d < 64; d <<= 1) {
        unsigned t = __shfl_up(x, d, 64);
        if (lane >= d) x += t;
    }
    __shared__ unsigned wsum[4];
    if (lane == 63) wsum[wid] = x;
    __syncthreads();
    unsigned woff = 0;
    for (int i = 0; i < wid; ++i) woff += wsum[i];
    unsigned incl = x + woff;
    if (tid == 255) *total = incl;
    return incl - v;
}

__global__ __launch_bounds__(256) void scan1_kernel(
    const unsigned* __restrict__ counts, unsigned* __restrict__ offs_local,
    unsigned* __restrict__ partials)
{
    int n = blockIdx.x * 256 + threadIdx.x;
    unsigned v = (n < N_NODES) ? counts[n] : 0u;
    __shared__ unsigned tot;
    unsigned excl = block_excl_scan(v, &tot, threadIdx.x);
    if (n < N_NODES) offs_local[n] = excl;
    __syncthreads();
    if (threadIdx.x == 0) partials[blockIdx.x] = tot;
}

__global__ __launch_bounds__(256) void scan2_kernel(
    unsigned* __restrict__ partials, unsigned* __restrict__ pscan)
{
    int i = threadIdx.x;
    unsigned v = (i < SCAN_BLOCKS) ? partials[i] : 0u;
    __shared__ unsigned tot;
    unsigned excl = block_excl_scan(v, &tot, i);
    if (i < SCAN_BLOCKS) pscan[i] = excl;
}

__global__ __launch_bounds__(256) void scan3_kernel(
    const unsigned* __restrict__ offs_local, const unsigned* __restrict__ pscan,
    unsigned* __restrict__ offs, unsigned* __restrict__ cursor)
{
    int n = blockIdx.x * 256 + threadIdx.x;
    if (n >= N_NODES) return;
    unsigned o = offs_local[n] + pscan[blockIdx.x];
    offs[n] = o;
    cursor[n] = o;
}

// ---------------- Kernel D: alpha + CSR scatter (1 thread per edge) -------
__global__ __launch_bounds__(256) void scatter_kernel(
    const int* __restrict__ ei, const float* __restrict__ ea,
    const float* __restrict__ s_src, const float* __restrict__ s_dst,
    unsigned* __restrict__ cursor, int2* __restrict__ csr,
    float* __restrict__ alpha)
{
    int e = blockIdx.x * 256 + threadIdx.x;
    if (e >= N_EDGES) return;
    const int r = ei[e];
    const int c = ei[N_EDGES + e];

    float4 ss = ((const float4*)s_src)[r];
    float4 sd = ((const float4*)s_dst)[c];
    float4 eav = ((const float4*)ea)[e];
    float4 a;
    a.x = leaky(ss.x + sd.x) * eav.x;
    a.y = leaky(ss.y + sd.y) * eav.y;
    a.z = leaky(ss.z + sd.z) * eav.z;
    a.w = leaky(ss.w + sd.w) * eav.w;
    ((float4*)alpha)[e] = a;

    unsigned pos = atomicAdd(&cursor[r], 1u);
    csr[pos] = make_int2(c, e);
}

// ---------------- Kernel E: atomic-free gather (1 wave per node) ----------
__global__ __launch_bounds__(256) void gather_kernel(
    const float* __restrict__ h, const float* __restrict__ s_src,
    const float* __restrict__ s_dst, const float* __restrict__ bias,
    const unsigned* __restrict__ offs, const unsigned* __restrict__ counts,
    const int2* __restrict__ csr, float* __restrict__ alpha,
    float* __restrict__ out, float* __restrict__ eif)
{
    const int tid = threadIdx.x;
    const int n = blockIdx.x * 4 + (tid >> 6);
    if (n >= N_NODES) return;
    const int lane = tid & 63, hd = lane >> 4;

    // self-loop contribution (ea = 1) + bias
    float s_self = s_src[n * HEADS + hd] + s_dst[n * HEADS + hd];
    float acc = bias[lane] + leaky(s_self) * h[(size_t)n * HC + lane];

    const unsigned start = offs[n];
    const int cnt = (int)counts[n];

    int i = 0;
    for (; i + 1 < cnt; i += 2) {
        int2 s0 = csr[start + i];
        int2 s1 = csr[start + i + 1];
        float a0 = alpha[(size_t)s0.y * HEADS + hd];
        float a1 = alpha[(size_t)s1.y * HEADS + hd];
        float h0 = h[(size_t)s0.x * HC + lane];
        float h1 = h[(size_t)s1.x * HC + lane];
        acc = fmaf(a0, h0, acc);
        acc = fmaf(a1, h1, acc);
    }
    if (i < cnt) {
        int2 s0 = csr[start + i];
        float a0 = alpha[(size_t)s0.y * HEADS + hd];
        float h0 = h[(size_t)s0.x * HC + lane];
        acc = fmaf(a0, h0, acc);
    }
    out[(size_t)n * HC + lane] = acc;

    // tails: self-loop alpha and edge_index_full loop entries
    if (lane < HEADS) {
        float s2 = s_src[n * HEADS + lane] + s_dst[n * HEADS + lane];
        alpha[(size_t)(N_EDGES + n) * HEADS + lane] = leaky(s2);
    }
    if (lane == 4) eif[N_EDGES + n] = (float)n;
    if (lane == 5) eif[(size_t)E_FULL + N_EDGES + n] = (float)n;
}

extern "C" void kernel_launch(void* const* d_in, const int* in_sizes, int n_in,
                              void* d_out, int out_size, void* d_ws, size_t ws_size,
                              hipStream_t stream) {
    const float* x      = (const float*)d_in[0];
    const int*   ei     = (const int*)  d_in[1];
    const float* ea     = (const float*)d_in[2];
    const float* weight = (const float*)d_in[3];
    const float* att    = (const float*)d_in[4];
    const float* bias   = (const float*)d_in[5];

    float* out   = (float*)d_out;                    // N_NODES*HC
    float* eif   = out + (size_t)N_NODES * HC;       // 2*E_FULL (as float)
    float* alpha = eif + (size_t)2 * E_FULL;         // E_FULL*HEADS

    float* h     = (float*)d_ws;                         // 3.2M floats
    float* s_src = h + (size_t)N_NODES * HC;             // 0.2M
    float* s_dst = s_src + (size_t)N_NODES * HEADS;      // 0.2M
    unsigned* counts     = (unsigned*)(s_dst + (size_t)N_NODES * HEADS);
    unsigned* offs_local = counts + N_NODES;
    unsigned* offs       = offs_local + N_NODES;
    unsigned* cursor     = offs + N_NODES;
    unsigned* partials   = cursor + N_NODES;
    unsigned* pscan      = partials + 256;
    int2*     csr        = (int2*)(pscan + 256);         // N_EDGES int2

    (void)hipMemsetAsync(counts, 0, N_NODES * sizeof(unsigned), stream);

    gemm_h_kernel<<<(N_NODES + 3) / 4, 256, 0, stream>>>(x, weight, att, h, s_src, s_dst);
    hist_kernel<<<(N_EDGES + 255) / 256, 256, 0, stream>>>(ei, counts, eif);
    scan1_kernel<<<SCAN_BLOCKS, 256, 0, stream>>>(counts, offs_local, partials);
    scan2_kernel<<<1, 256, 0, stream>>>(partials, pscan);
    scan3_kernel<<<SCAN_BLOCKS, 256, 0, stream>>>(offs_local, pscan, offs, cursor);
    scatter_kernel<<<(N_EDGES + 255) / 256, 256, 0, stream>>>(
        ei, ea, s_src, s_dst, cursor, csr, alpha);
    gather_kernel<<<(N_NODES + 3) / 4, 256, 0, stream>>>(
        h, s_src, s_dst, bias, offs, counts, csr, alpha, out, eif);
}

// Round 4
// 309.851 us; speedup vs baseline: 1.5905x; 1.0413x over previous
//
#include <hip/hip_runtime.h>

#define N_NODES 50000
#define N_EDGES 1600000
#define IN_CH 128
#define HEADS 4
#define OUT_CH 16
#define HC 64                      // HEADS*OUT_CH
#define E_FULL (N_EDGES + N_NODES)
#define NEG_SLOPE 0.2f
#define SCAN_BLOCKS ((N_NODES + 255) / 256)   // 196

__device__ __forceinline__ float leaky(float s) { return s >= 0.f ? s : NEG_SLOPE * s; }

__device__ __forceinline__ unsigned short f2bf(float f) {  // round-to-nearest-even
    unsigned u = __float_as_uint(f);
    return (unsigned short)((u + 0x7fffu + ((u >> 16) & 1u)) >> 16);
}
__device__ __forceinline__ float bf2f(unsigned short v) {
    return __uint_as_float(((unsigned)v) << 16);
}

// ---------------- Kernel A: h = x @ W (bf16 out), fused attention scalars --
__global__ __launch_bounds__(256) void gemm_h_kernel(
    const float* __restrict__ x, const float* __restrict__ weight,
    const float* __restrict__ att, unsigned short* __restrict__ h16,
    float* __restrict__ s_src, float* __restrict__ s_dst)
{
    __shared__ float w_lds[IN_CH * HC];   // 32 KB
    __shared__ float x_lds[8 * IN_CH];    // 4 KB
    const int tid = threadIdx.x;
    const int nbase = blockIdx.x * 8;

    for (int i = tid; i < IN_CH * HC; i += 256) w_lds[i] = weight[i];
    for (int i = tid; i < 8 * IN_CH; i += 256) {
        int n = nbase + i / IN_CH;
        x_lds[i] = (n < N_NODES) ? x[(size_t)n * IN_CH + (i % IN_CH)] : 0.f;
    }
    __syncthreads();

    const int w = tid >> 6;        // wave id
    const int lane = tid & 63;     // output channel
    const int n0 = nbase + w;      // two nodes per wave
    const int n1 = nbase + 4 + w;

    float acc0 = 0.f, acc1 = 0.f;
    #pragma unroll 8
    for (int k = 0; k < IN_CH; ++k) {
        float wv = w_lds[k * HC + lane];
        acc0 = fmaf(x_lds[w * IN_CH + k], wv, acc0);
        acc1 = fmaf(x_lds[(w + 4) * IN_CH + k], wv, acc1);
    }

    if (n0 < N_NODES) h16[(size_t)n0 * HC + lane] = f2bf(acc0);
    if (n1 < N_NODES) h16[(size_t)n1 * HC + lane] = f2bf(acc1);

    const int hd = lane >> 4, c = lane & 15;
    float as = att[hd * 32 + c], ad = att[hd * 32 + 16 + c];
    float ts0 = acc0 * as, td0 = acc0 * ad;
    float ts1 = acc1 * as, td1 = acc1 * ad;
    #pragma unroll
    for (int m = 8; m >= 1; m >>= 1) {
        ts0 += __shfl_xor(ts0, m, 64);
        td0 += __shfl_xor(td0, m, 64);
        ts1 += __shfl_xor(ts1, m, 64);
        td1 += __shfl_xor(td1, m, 64);
    }
    if (c == 0) {
        if (n0 < N_NODES) { s_src[n0 * HEADS + hd] = ts0; s_dst[n0 * HEADS + hd] = td0; }
        if (n1 < N_NODES) { s_src[n1 * HEADS + hd] = ts1; s_dst[n1 * HEADS + hd] = td1; }
    }
}

// ---------------- Kernel B: row histogram + edge_index_full output ---------
__global__ __launch_bounds__(256) void hist_kernel(
    const int* __restrict__ ei, unsigned* __restrict__ counts,
    float* __restrict__ eif)
{
    int e = blockIdx.x * 256 + threadIdx.x;
    if (e >= N_EDGES) return;
    const int r = ei[e];
    const int c = ei[N_EDGES + e];
    atomicAdd(&counts[r], 1u);
    eif[e] = (float)r;
    eif[(size_t)E_FULL + e] = (float)c;
}

// ---------------- Scan: counts -> exclusive offsets ------------------------
__device__ __forceinline__ unsigned block_excl_scan(unsigned v, unsigned* total,
                                                    int tid) {
    const int lane = tid & 63, wid = tid >> 6;
    unsigned x = v;
    #pragma unroll
    for (int d = 1; d < 64; d <<= 1) {
        unsigned t = __shfl_up(x, d, 64);
        if (lane >= d) x += t;
    }
    __shared__ unsigned wsum[4];
    if (lane == 63) wsum[wid] = x;
    __syncthreads();
    unsigned woff = 0;
    for (int i = 0; i < wid; ++i) woff += wsum[i];
    unsigned incl = x + woff;
    if (tid == 255) *total = incl;
    return incl - v;
}

__global__ __launch_bounds__(256) void scan1_kernel(
    const unsigned* __restrict__ counts, unsigned* __restrict__ offs_local,
    unsigned* __restrict__ partials)
{
    int n = blockIdx.x * 256 + threadIdx.x;
    unsigned v = (n < N_NODES) ? counts[n] : 0u;
    __shared__ unsigned tot;
    unsigned excl = block_excl_scan(v, &tot, threadIdx.x);
    if (n < N_NODES) offs_local[n] = excl;
    __syncthreads();
    if (threadIdx.x == 0) partials[blockIdx.x] = tot;
}

__global__ __launch_bounds__(256) void scan2_kernel(
    unsigned* __restrict__ partials, unsigned* __restrict__ pscan)
{
    int i = threadIdx.x;
    unsigned v = (i < SCAN_BLOCKS) ? partials[i] : 0u;
    __shared__ unsigned tot;
    unsigned excl = block_excl_scan(v, &tot, i);
    if (i < SCAN_BLOCKS) pscan[i] = excl;
}

__global__ __launch_bounds__(256) void scan3_kernel(
    const unsigned* __restrict__ offs_local, const unsigned* __restrict__ pscan,
    unsigned* __restrict__ offs, unsigned* __restrict__ cursor)
{
    int n = blockIdx.x * 256 + threadIdx.x;
    if (n >= N_NODES) return;
    unsigned o = offs_local[n] + pscan[blockIdx.x];
    offs[n] = o;
    cursor[n] = o;
}

// ---------------- Kernel D: alpha + slot-ordered (bf16 alpha, col) --------
__global__ __launch_bounds__(256) void scatter_kernel(
    const int* __restrict__ ei, const float* __restrict__ ea,
    const float* __restrict__ s_src, const float* __restrict__ s_dst,
    unsigned* __restrict__ cursor, uint2* __restrict__ ab,
    int* __restrict__ ccol, float* __restrict__ alpha)
{
    int e = blockIdx.x * 256 + threadIdx.x;
    if (e >= N_EDGES) return;
    const int r = ei[e];
    const int c = ei[N_EDGES + e];

    float4 ss = ((const float4*)s_src)[r];
    float4 sd = ((const float4*)s_dst)[c];
    float4 eav = ((const float4*)ea)[e];
    float4 a;
    a.x = leaky(ss.x + sd.x) * eav.x;
    a.y = leaky(ss.y + sd.y) * eav.y;
    a.z = leaky(ss.z + sd.z) * eav.z;
    a.w = leaky(ss.w + sd.w) * eav.w;
    ((float4*)alpha)[e] = a;

    uint2 p;
    p.x = (unsigned)f2bf(a.x) | ((unsigned)f2bf(a.y) << 16);
    p.y = (unsigned)f2bf(a.z) | ((unsigned)f2bf(a.w) << 16);

    unsigned pos = atomicAdd(&cursor[r], 1u);
    ab[pos] = p;
    ccol[pos] = c;
}

// ---------------- Kernel E: atomic-free gather (1 wave per node) ----------
__global__ __launch_bounds__(256) void gather_kernel(
    const unsigned short* __restrict__ h16, const float* __restrict__ s_src,
    const float* __restrict__ s_dst, const float* __restrict__ bias,
    const unsigned* __restrict__ offs, const unsigned* __restrict__ counts,
    const uint2* __restrict__ ab, const int* __restrict__ ccol,
    float* __restrict__ alpha, float* __restrict__ out, float* __restrict__ eif)
{
    const int tid = threadIdx.x;
    const int n = blockIdx.x * 4 + (tid >> 6);
    if (n >= N_NODES) return;
    const int lane = tid & 63, hd = lane >> 4;

    // self-loop contribution (ea = 1) + bias
    float s_self = s_src[n * HEADS + hd] + s_dst[n * HEADS + hd];
    float acc = bias[lane] + leaky(s_self) * bf2f(h16[(size_t)n * HC + lane]);

    const unsigned start = offs[n];
    const int cnt = (int)counts[n];

    int i = 0;
    for (; i + 1 < cnt; i += 2) {
        int c0 = ccol[start + i];
        int c1 = ccol[start + i + 1];
        uint2 p0 = ab[start + i];
        uint2 p1 = ab[start + i + 1];
        unsigned w0 = (hd & 2) ? p0.y : p0.x;
        unsigned w1 = (hd & 2) ? p1.y : p1.x;
        float a0 = bf2f((unsigned short)((hd & 1) ? (w0 >> 16) : (w0 & 0xffffu)));
        float a1 = bf2f((unsigned short)((hd & 1) ? (w1 >> 16) : (w1 & 0xffffu)));
        float h0 = bf2f(h16[(size_t)c0 * HC + lane]);
        float h1 = bf2f(h16[(size_t)c1 * HC + lane]);
        acc = fmaf(a0, h0, acc);
        acc = fmaf(a1, h1, acc);
    }
    if (i < cnt) {
        int c0 = ccol[start + i];
        uint2 p0 = ab[start + i];
        unsigned w0 = (hd & 2) ? p0.y : p0.x;
        float a0 = bf2f((unsigned short)((hd & 1) ? (w0 >> 16) : (w0 & 0xffffu)));
        float h0 = bf2f(h16[(size_t)c0 * HC + lane]);
        acc = fmaf(a0, h0, acc);
    }
    out[(size_t)n * HC + lane] = acc;

    // tails: self-loop alpha and edge_index_full loop entries
    if (lane < HEADS) {
        float s2 = s_src[n * HEADS + lane] + s_dst[n * HEADS + lane];
        alpha[(size_t)(N_EDGES + n) * HEADS + lane] = leaky(s2);
    }
    if (lane == 4) eif[N_EDGES + n] = (float)n;
    if (lane == 5) eif[(size_t)E_FULL + N_EDGES + n] = (float)n;
}

extern "C" void kernel_launch(void* const* d_in, const int* in_sizes, int n_in,
                              void* d_out, int out_size, void* d_ws, size_t ws_size,
                              hipStream_t stream) {
    const float* x      = (const float*)d_in[0];
    const int*   ei     = (const int*)  d_in[1];
    const float* ea     = (const float*)d_in[2];
    const float* weight = (const float*)d_in[3];
    const float* att    = (const float*)d_in[4];
    const float* bias   = (const float*)d_in[5];

    float* out   = (float*)d_out;                    // N_NODES*HC
    float* eif   = out + (size_t)N_NODES * HC;       // 2*E_FULL (as float)
    float* alpha = eif + (size_t)2 * E_FULL;         // E_FULL*HEADS

    unsigned short* h16 = (unsigned short*)d_ws;                 // 6.4 MB
    float* s_src = (float*)(h16 + (size_t)N_NODES * HC);         // 0.8 MB
    float* s_dst = s_src + (size_t)N_NODES * HEADS;              // 0.8 MB
    unsigned* counts     = (unsigned*)(s_dst + (size_t)N_NODES * HEADS);
    unsigned* offs_local = counts + N_NODES;
    unsigned* offs       = offs_local + N_NODES;
    unsigned* cursor     = offs + N_NODES;
    unsigned* partials   = cursor + N_NODES;
    unsigned* pscan      = partials + 256;
    uint2*    ab         = (uint2*)(pscan + 256);                // 12.8 MB
    int*      ccol       = (int*)(ab + (size_t)N_EDGES);         // 6.4 MB

    (void)hipMemsetAsync(counts, 0, N_NODES * sizeof(unsigned), stream);

    gemm_h_kernel<<<(N_NODES + 7) / 8, 256, 0, stream>>>(x, weight, att, h16, s_src, s_dst);
    hist_kernel<<<(N_EDGES + 255) / 256, 256, 0, stream>>>(ei, counts, eif);
    scan1_kernel<<<SCAN_BLOCKS, 256, 0, stream>>>(counts, offs_local, partials);
    scan2_kernel<<<1, 256, 0, stream>>>(partials, pscan);
    scan3_kernel<<<SCAN_BLOCKS, 256, 0, stream>>>(offs_local, pscan, offs, cursor);
    scatter_kernel<<<(N_EDGES + 255) / 256, 256, 0, stream>>>(
        ei, ea, s_src, s_dst, cursor, ab, ccol, alpha);
    gather_kernel<<<(N_NODES + 3) / 4, 256, 0, stream>>>(
        h16, s_src, s_dst, bias, offs, counts, ab, ccol, alpha, out, eif);
}

// Round 5
// 277.019 us; speedup vs baseline: 1.7791x; 1.1185x over previous
//
#include <hip/hip_runtime.h>

#define N_NODES 50000
#define N_EDGES 1600000
#define IN_CH 128
#define HEADS 4
#define HC 64                      // HEADS*OUT_CH
#define E_FULL (N_EDGES + N_NODES)
#define NEG_SLOPE 0.2f
#define NCHAIN 4                   // interleaved lists per node (MLP for the walk)

__device__ __forceinline__ float leaky(float s) { return s >= 0.f ? s : NEG_SLOPE * s; }

__device__ __forceinline__ unsigned f2bf(float f) {  // round-to-nearest-even
    unsigned u = __float_as_uint(f);
    return (u + 0x7fffu + ((u >> 16) & 1u)) >> 16;
}
__device__ __forceinline__ float bf2f(unsigned v) {
    return __uint_as_float(v << 16);
}

// ---------------- Kernel A: h = x @ W (bf16 out), fused attention scalars --
__global__ __launch_bounds__(256) void gemm_h_kernel(
    const float* __restrict__ x, const float* __restrict__ weight,
    const float* __restrict__ att, unsigned short* __restrict__ h16,
    float* __restrict__ s_src, float* __restrict__ s_dst)
{
    __shared__ float w_lds[IN_CH * HC];   // 32 KB
    __shared__ float x_lds[8 * IN_CH];    // 4 KB
    const int tid = threadIdx.x;
    const int nbase = blockIdx.x * 8;

    for (int i = tid; i < IN_CH * HC; i += 256) w_lds[i] = weight[i];
    for (int i = tid; i < 8 * IN_CH; i += 256) {
        int n = nbase + i / IN_CH;
        x_lds[i] = (n < N_NODES) ? x[(size_t)n * IN_CH + (i % IN_CH)] : 0.f;
    }
    __syncthreads();

    const int w = tid >> 6;        // wave id
    const int lane = tid & 63;     // output channel
    const int n0 = nbase + w;      // two nodes per wave
    const int n1 = nbase + 4 + w;

    float acc0 = 0.f, acc1 = 0.f;
    #pragma unroll 8
    for (int k = 0; k < IN_CH; ++k) {
        float wv = w_lds[k * HC + lane];
        acc0 = fmaf(x_lds[w * IN_CH + k], wv, acc0);
        acc1 = fmaf(x_lds[(w + 4) * IN_CH + k], wv, acc1);
    }

    if (n0 < N_NODES) h16[(size_t)n0 * HC + lane] = (unsigned short)f2bf(acc0);
    if (n1 < N_NODES) h16[(size_t)n1 * HC + lane] = (unsigned short)f2bf(acc1);

    const int hd = lane >> 4, c = lane & 15;
    float as = att[hd * 32 + c], ad = att[hd * 32 + 16 + c];
    float ts0 = acc0 * as, td0 = acc0 * ad;
    float ts1 = acc1 * as, td1 = acc1 * ad;
    #pragma unroll
    for (int m = 8; m >= 1; m >>= 1) {
        ts0 += __shfl_xor(ts0, m, 64);
        td0 += __shfl_xor(td0, m, 64);
        ts1 += __shfl_xor(ts1, m, 64);
        td1 += __shfl_xor(td1, m, 64);
    }
    if (c == 0) {
        if (n0 < N_NODES) { s_src[n0 * HEADS + hd] = ts0; s_dst[n0 * HEADS + hd] = td0; }
        if (n1 < N_NODES) { s_src[n1 * HEADS + hd] = ts1; s_dst[n1 * HEADS + hd] = td1; }
    }
}

// ---------------- Kernel B: build linked lists + alpha + edge_index_full ---
// All large writes are SEQUENTIAL (indexed by e). Only atomicExch on the
// 800 KB head array is random (L2-resident).
__global__ __launch_bounds__(256) void build_kernel(
    const int* __restrict__ ei, const float* __restrict__ ea,
    const float* __restrict__ s_src, const float* __restrict__ s_dst,
    unsigned* __restrict__ head, uint4* __restrict__ pay,
    float* __restrict__ alpha, float* __restrict__ eif)
{
    int e = blockIdx.x * 256 + threadIdx.x;
    if (e >= N_EDGES) return;
    const int r = ei[e];
    const int c = ei[N_EDGES + e];

    float4 ss = ((const float4*)s_src)[r];
    float4 sd = ((const float4*)s_dst)[c];
    float4 eav = ((const float4*)ea)[e];
    float4 a;
    a.x = leaky(ss.x + sd.x) * eav.x;
    a.y = leaky(ss.y + sd.y) * eav.y;
    a.z = leaky(ss.z + sd.z) * eav.z;
    a.w = leaky(ss.w + sd.w) * eav.w;
    ((float4*)alpha)[e] = a;

    eif[e] = (float)r;
    eif[(size_t)E_FULL + e] = (float)c;

    unsigned a01 = f2bf(a.x) | (f2bf(a.y) << 16);
    unsigned a23 = f2bf(a.z) | (f2bf(a.w) << 16);

    unsigned prev = atomicExch(&head[r * NCHAIN + (e & (NCHAIN - 1))], (unsigned)e);
    pay[e] = make_uint4((unsigned)c, a01, a23, prev);
}

// ---------------- Kernel C: gather by walking 4 chains per node -----------
__global__ __launch_bounds__(256) void gather_walk(
    const unsigned short* __restrict__ h16, const float* __restrict__ s_src,
    const float* __restrict__ s_dst, const float* __restrict__ bias,
    const unsigned* __restrict__ head, const uint4* __restrict__ pay,
    float* __restrict__ alpha, float* __restrict__ out, float* __restrict__ eif)
{
    const int tid = threadIdx.x;
    const int n = blockIdx.x * 4 + (tid >> 6);
    if (n >= N_NODES) return;
    const int lane = tid & 63, hd = lane >> 4;

    // self-loop contribution (ea = 1) + bias
    float s_self = s_src[n * HEADS + hd] + s_dst[n * HEADS + hd];
    float acc = bias[lane] + leaky(s_self) * bf2f(h16[(size_t)n * HC + lane]);

    int e0 = (int)head[n * NCHAIN + 0];
    int e1 = (int)head[n * NCHAIN + 1];
    int e2 = (int)head[n * NCHAIN + 2];
    int e3 = (int)head[n * NCHAIN + 3];

    while (e0 >= 0 || e1 >= 0 || e2 >= 0 || e3 >= 0) {
        uint4 P0, P1, P2, P3;
        if (e0 >= 0) P0 = pay[e0];
        if (e1 >= 0) P1 = pay[e1];
        if (e2 >= 0) P2 = pay[e2];
        if (e3 >= 0) P3 = pay[e3];
        if (e0 >= 0) {
            unsigned w = (hd & 2) ? P0.z : P0.y;
            float a = bf2f((hd & 1) ? (w >> 16) : (w & 0xffffu));
            float hv = bf2f(h16[(size_t)P0.x * HC + lane]);
            acc = fmaf(a, hv, acc);
            e0 = (int)P0.w;
        }
        if (e1 >= 0) {
            unsigned w = (hd & 2) ? P1.z : P1.y;
            float a = bf2f((hd & 1) ? (w >> 16) : (w & 0xffffu));
            float hv = bf2f(h16[(size_t)P1.x * HC + lane]);
            acc = fmaf(a, hv, acc);
            e1 = (int)P1.w;
        }
        if (e2 >= 0) {
            unsigned w = (hd & 2) ? P2.z : P2.y;
            float a = bf2f((hd & 1) ? (w >> 16) : (w & 0xffffu));
            float hv = bf2f(h16[(size_t)P2.x * HC + lane]);
            acc = fmaf(a, hv, acc);
            e2 = (int)P2.w;
        }
        if (e3 >= 0) {
            unsigned w = (hd & 2) ? P3.z : P3.y;
            float a = bf2f((hd & 1) ? (w >> 16) : (w & 0xffffu));
            float hv = bf2f(h16[(size_t)P3.x * HC + lane]);
            acc = fmaf(a, hv, acc);
            e3 = (int)P3.w;
        }
    }
    out[(size_t)n * HC + lane] = acc;

    // tails: self-loop alpha and edge_index_full loop entries
    if (lane < HEADS) {
        float s2 = s_src[n * HEADS + lane] + s_dst[n * HEADS + lane];
        alpha[(size_t)(N_EDGES + n) * HEADS + lane] = leaky(s2);
    }
    if (lane == 4) eif[N_EDGES + n] = (float)n;
    if (lane == 5) eif[(size_t)E_FULL + N_EDGES + n] = (float)n;
}

extern "C" void kernel_launch(void* const* d_in, const int* in_sizes, int n_in,
                              void* d_out, int out_size, void* d_ws, size_t ws_size,
                              hipStream_t stream) {
    const float* x      = (const float*)d_in[0];
    const int*   ei     = (const int*)  d_in[1];
    const float* ea     = (const float*)d_in[2];
    const float* weight = (const float*)d_in[3];
    const float* att    = (const float*)d_in[4];
    const float* bias   = (const float*)d_in[5];

    float* out   = (float*)d_out;                    // N_NODES*HC
    float* eif   = out + (size_t)N_NODES * HC;       // 2*E_FULL (as float)
    float* alpha = eif + (size_t)2 * E_FULL;         // E_FULL*HEADS

    unsigned short* h16 = (unsigned short*)d_ws;                 // 6.4 MB
    float* s_src = (float*)(h16 + (size_t)N_NODES * HC);         // 0.8 MB
    float* s_dst = s_src + (size_t)N_NODES * HEADS;              // 0.8 MB
    unsigned* head = (unsigned*)(s_dst + (size_t)N_NODES * HEADS); // 0.8 MB
    uint4* pay = (uint4*)(head + (size_t)N_NODES * NCHAIN);      // 25.6 MB

    (void)hipMemsetAsync(head, 0xFF, (size_t)N_NODES * NCHAIN * sizeof(unsigned), stream);

    gemm_h_kernel<<<(N_NODES + 7) / 8, 256, 0, stream>>>(x, weight, att, h16, s_src, s_dst);
    build_kernel<<<(N_EDGES + 255) / 256, 256, 0, stream>>>(
        ei, ea, s_src, s_dst, head, pay, alpha, eif);
    gather_walk<<<(N_NODES + 3) / 4, 256, 0, stream>>>(
        h16, s_src, s_dst, bias, head, pay, alpha, out, eif);
}

// Round 6
// 274.989 us; speedup vs baseline: 1.7922x; 1.0074x over previous
//
#include <hip/hip_runtime.h>

#define N_NODES 50000
#define N_EDGES 1600000
#define IN_CH 128
#define HEADS 4
#define HC 64                      // HEADS*OUT_CH
#define E_FULL (N_EDGES + N_NODES)
#define NEG_SLOPE 0.2f
#define SCAN_BLOCKS ((N_NODES + 255) / 256)   // 196

__device__ __forceinline__ float leaky(float s) { return s >= 0.f ? s : NEG_SLOPE * s; }

__device__ __forceinline__ unsigned f2bf(float f) {  // round-to-nearest-even
    unsigned u = __float_as_uint(f);
    return (u + 0x7fffu + ((u >> 16) & 1u)) >> 16;
}
__device__ __forceinline__ float bf2f(unsigned v) {
    return __uint_as_float(v << 16);
}

// ---------------- Kernel A: h = x @ W (bf16 out), fused attention scalars --
__global__ __launch_bounds__(256) void gemm_h_kernel(
    const float* __restrict__ x, const float* __restrict__ weight,
    const float* __restrict__ att, unsigned short* __restrict__ h16,
    float* __restrict__ s_src, float* __restrict__ s_dst)
{
    __shared__ float w_lds[IN_CH * HC];   // 32 KB
    __shared__ float x_lds[8 * IN_CH];    // 4 KB
    const int tid = threadIdx.x;
    const int nbase = blockIdx.x * 8;

    for (int i = tid; i < IN_CH * HC; i += 256) w_lds[i] = weight[i];
    for (int i = tid; i < 8 * IN_CH; i += 256) {
        int n = nbase + i / IN_CH;
        x_lds[i] = (n < N_NODES) ? x[(size_t)n * IN_CH + (i % IN_CH)] : 0.f;
    }
    __syncthreads();

    const int w = tid >> 6;        // wave id
    const int lane = tid & 63;     // output channel
    const int n0 = nbase + w;      // two nodes per wave
    const int n1 = nbase + 4 + w;

    float acc0 = 0.f, acc1 = 0.f;
    #pragma unroll 8
    for (int k = 0; k < IN_CH; ++k) {
        float wv = w_lds[k * HC + lane];
        acc0 = fmaf(x_lds[w * IN_CH + k], wv, acc0);
        acc1 = fmaf(x_lds[(w + 4) * IN_CH + k], wv, acc1);
    }

    if (n0 < N_NODES) h16[(size_t)n0 * HC + lane] = (unsigned short)f2bf(acc0);
    if (n1 < N_NODES) h16[(size_t)n1 * HC + lane] = (unsigned short)f2bf(acc1);

    const int hd = lane >> 4, c = lane & 15;
    float as = att[hd * 32 + c], ad = att[hd * 32 + 16 + c];
    float ts0 = acc0 * as, td0 = acc0 * ad;
    float ts1 = acc1 * as, td1 = acc1 * ad;
    #pragma unroll
    for (int m = 8; m >= 1; m >>= 1) {
        ts0 += __shfl_xor(ts0, m, 64);
        td0 += __shfl_xor(td0, m, 64);
        ts1 += __shfl_xor(ts1, m, 64);
        td1 += __shfl_xor(td1, m, 64);
    }
    if (c == 0) {
        if (n0 < N_NODES) { s_src[n0 * HEADS + hd] = ts0; s_dst[n0 * HEADS + hd] = td0; }
        if (n1 < N_NODES) { s_src[n1 * HEADS + hd] = ts1; s_dst[n1 * HEADS + hd] = td1; }
    }
}

// ---------------- Kernel B: row histogram + edge_index_full output ---------
__global__ __launch_bounds__(256) void hist_kernel(
    const int* __restrict__ ei, unsigned* __restrict__ counts,
    float* __restrict__ eif)
{
    int e = blockIdx.x * 256 + threadIdx.x;
    if (e >= N_EDGES) return;
    const int r = ei[e];
    const int c = ei[N_EDGES + e];
    atomicAdd(&counts[r], 1u);
    eif[e] = (float)r;
    eif[(size_t)E_FULL + e] = (float)c;
}

// ---------------- Scan: counts -> exclusive offsets ------------------------
__device__ __forceinline__ unsigned block_excl_scan(unsigned v, unsigned* total,
                                                    int tid) {
    const int lane = tid & 63, wid = tid >> 6;
    unsigned x = v;
    #pragma unroll
    for (int d = 1; d < 64; d <<= 1) {
        unsigned t = __shfl_up(x, d, 64);
        if (lane >= d) x += t;
    }
    __shared__ unsigned wsum[4];
    if (lane == 63) wsum[wid] = x;
    __syncthreads();
    unsigned woff = 0;
    for (int i = 0; i < wid; ++i) woff += wsum[i];
    unsigned incl = x + woff;
    if (tid == 255) *total = incl;
    return incl - v;
}

__global__ __launch_bounds__(256) void scan1_kernel(
    const unsigned* __restrict__ counts, unsigned* __restrict__ offs_local,
    unsigned* __restrict__ partials)
{
    int n = blockIdx.x * 256 + threadIdx.x;
    unsigned v = (n < N_NODES) ? counts[n] : 0u;
    __shared__ unsigned tot;
    unsigned excl = block_excl_scan(v, &tot, threadIdx.x);
    if (n < N_NODES) offs_local[n] = excl;
    __syncthreads();
    if (threadIdx.x == 0) partials[blockIdx.x] = tot;
}

__global__ __launch_bounds__(256) void scan2_kernel(
    unsigned* __restrict__ partials, unsigned* __restrict__ pscan)
{
    int i = threadIdx.x;
    unsigned v = (i < SCAN_BLOCKS) ? partials[i] : 0u;
    __shared__ unsigned tot;
    unsigned excl = block_excl_scan(v, &tot, i);
    if (i < SCAN_BLOCKS) pscan[i] = excl;
}

__global__ __launch_bounds__(256) void scan3_kernel(
    const unsigned* __restrict__ offs_local, const unsigned* __restrict__ pscan,
    unsigned* __restrict__ offs, unsigned* __restrict__ cursor)
{
    int n = blockIdx.x * 256 + threadIdx.x;
    if (n >= N_NODES) return;
    unsigned o = offs_local[n] + pscan[blockIdx.x];
    offs[n] = o;
    cursor[n] = o;
}

// ---------------- Kernel D: alpha + single-uint4 CSR slot scatter ---------
__global__ __launch_bounds__(256) void scatter_kernel(
    const int* __restrict__ ei, const float* __restrict__ ea,
    const float* __restrict__ s_src, const float* __restrict__ s_dst,
    unsigned* __restrict__ cursor, uint4* __restrict__ slots,
    float* __restrict__ alpha)
{
    int e = blockIdx.x * 256 + threadIdx.x;
    if (e >= N_EDGES) return;
    const int r = ei[e];
    const int c = ei[N_EDGES + e];

    float4 ss = ((const float4*)s_src)[r];
    float4 sd = ((const float4*)s_dst)[c];
    float4 eav = ((const float4*)ea)[e];
    float4 a;
    a.x = leaky(ss.x + sd.x) * eav.x;
    a.y = leaky(ss.y + sd.y) * eav.y;
    a.z = leaky(ss.z + sd.z) * eav.z;
    a.w = leaky(ss.w + sd.w) * eav.w;
    ((float4*)alpha)[e] = a;

    unsigned a01 = f2bf(a.x) | (f2bf(a.y) << 16);
    unsigned a23 = f2bf(a.z) | (f2bf(a.w) << 16);

    unsigned pos = atomicAdd(&cursor[r], 1u);
    slots[pos] = make_uint4((unsigned)c, a01, a23, 0u);
}

// ---------------- Kernel E: atomic-free gather (1 wave per node) ----------
__device__ __forceinline__ float slot_alpha(uint4 s, int hd) {
    unsigned w = (hd & 2) ? s.z : s.y;
    return bf2f((hd & 1) ? (w >> 16) : (w & 0xffffu));
}

__global__ __launch_bounds__(256) void gather_kernel(
    const unsigned short* __restrict__ h16, const float* __restrict__ s_src,
    const float* __restrict__ s_dst, const float* __restrict__ bias,
    const unsigned* __restrict__ offs, const unsigned* __restrict__ counts,
    const uint4* __restrict__ slots, float* __restrict__ alpha,
    float* __restrict__ out, float* __restrict__ eif)
{
    const int tid = threadIdx.x;
    const int n = blockIdx.x * 4 + (tid >> 6);
    if (n >= N_NODES) return;
    const int lane = tid & 63, hd = lane >> 4;

    // self-loop contribution (ea = 1) + bias
    float s_self = s_src[n * HEADS + hd] + s_dst[n * HEADS + hd];
    float acc = bias[lane] + leaky(s_self) * bf2f(h16[(size_t)n * HC + lane]);

    const unsigned start = offs[n];
    const int cnt = (int)counts[n];

    int i = 0;
    for (; i + 3 < cnt; i += 4) {
        uint4 s0 = slots[start + i];
        uint4 s1 = slots[start + i + 1];
        uint4 s2 = slots[start + i + 2];
        uint4 s3 = slots[start + i + 3];
        float h0 = bf2f(h16[(size_t)s0.x * HC + lane]);
        float h1 = bf2f(h16[(size_t)s1.x * HC + lane]);
        float h2 = bf2f(h16[(size_t)s2.x * HC + lane]);
        float h3 = bf2f(h16[(size_t)s3.x * HC + lane]);
        acc = fmaf(slot_alpha(s0, hd), h0, acc);
        acc = fmaf(slot_alpha(s1, hd), h1, acc);
        acc = fmaf(slot_alpha(s2, hd), h2, acc);
        acc = fmaf(slot_alpha(s3, hd), h3, acc);
    }
    for (; i < cnt; ++i) {
        uint4 s0 = slots[start + i];
        float h0 = bf2f(h16[(size_t)s0.x * HC + lane]);
        acc = fmaf(slot_alpha(s0, hd), h0, acc);
    }
    out[(size_t)n * HC + lane] = acc;

    // tails: self-loop alpha and edge_index_full loop entries
    if (lane < HEADS) {
        float s2 = s_src[n * HEADS + lane] + s_dst[n * HEADS + lane];
        alpha[(size_t)(N_EDGES + n) * HEADS + lane] = leaky(s2);
    }
    if (lane == 4) eif[N_EDGES + n] = (float)n;
    if (lane == 5) eif[(size_t)E_FULL + N_EDGES + n] = (float)n;
}

extern "C" void kernel_launch(void* const* d_in, const int* in_sizes, int n_in,
                              void* d_out, int out_size, void* d_ws, size_t ws_size,
                              hipStream_t stream) {
    const float* x      = (const float*)d_in[0];
    const int*   ei     = (const int*)  d_in[1];
    const float* ea     = (const float*)d_in[2];
    const float* weight = (const float*)d_in[3];
    const float* att    = (const float*)d_in[4];
    const float* bias   = (const float*)d_in[5];

    float* out   = (float*)d_out;                    // N_NODES*HC
    float* eif   = out + (size_t)N_NODES * HC;       // 2*E_FULL (as float)
    float* alpha = eif + (size_t)2 * E_FULL;         // E_FULL*HEADS

    unsigned short* h16 = (unsigned short*)d_ws;                 // 6.4 MB
    float* s_src = (float*)(h16 + (size_t)N_NODES * HC);         // 0.8 MB
    float* s_dst = s_src + (size_t)N_NODES * HEADS;              // 0.8 MB
    unsigned* counts     = (unsigned*)(s_dst + (size_t)N_NODES * HEADS);
    unsigned* offs_local = counts + N_NODES;
    unsigned* offs       = offs_local + N_NODES;
    unsigned* cursor     = offs + N_NODES;
    unsigned* partials   = cursor + N_NODES;
    unsigned* pscan      = partials + 256;
    uint4*    slots      = (uint4*)(pscan + 256);                // 25.6 MB

    (void)hipMemsetAsync(counts, 0, N_NODES * sizeof(unsigned), stream);

    gemm_h_kernel<<<(N_NODES + 7) / 8, 256, 0, stream>>>(x, weight, att, h16, s_src, s_dst);
    hist_kernel<<<(N_EDGES + 255) / 256, 256, 0, stream>>>(ei, counts, eif);
    scan1_kernel<<<SCAN_BLOCKS, 256, 0, stream>>>(counts, offs_local, partials);
    scan2_kernel<<<1, 256, 0, stream>>>(partials, pscan);
    scan3_kernel<<<SCAN_BLOCKS, 256, 0, stream>>>(offs_local, pscan, offs, cursor);
    scatter_kernel<<<(N_EDGES + 255) / 256, 256, 0, stream>>>(
        ei, ea, s_src, s_dst, cursor, slots, alpha);
    gather_kernel<<<(N_NODES + 3) / 4, 256, 0, stream>>>(
        h16, s_src, s_dst, bias, offs, counts, slots, alpha, out, eif);
}